// Round 10
// baseline (213.800 us; speedup 1.0000x reference)
//
#include <hip/hip_runtime.h>
#include <math.h>

#define THRESH    0.5f
#define NEG_POSK  3
#define EPSf      1e-6f
#define CCLS      81
#define TILEA     32
#define CHUNKS    16
#define TPB       14      // tiles per block (k_conf)
#define NCH2      8       // chunks per batch (select pipeline)

__device__ __forceinline__ float iou_xy(float ax0, float ay0, float ax1, float ay1,
                                        float bx0, float by0, float bx1, float by1) {
    float lx = fmaxf(ax0, bx0), ly = fmaxf(ay0, by0);
    float rx = fminf(ax1, bx1), ry = fminf(ay1, by1);
    float w = fmaxf(rx - lx, 0.f), h = fmaxf(ry - ly, 0.f);
    float inter = w * h;
    float aa = (ax1 - ax0) * (ay1 - ay0);
    float ab = (bx1 - bx0) * (by1 - by0);
    return inter / (aa + ab - inter);
}

__device__ __forceinline__ void gload16(const void* g, void* l) {
    __builtin_amdgcn_global_load_lds(
        (const __attribute__((address_space(1))) void*)g,
        (__attribute__((address_space(3))) void*)l, 16, 0, 0);
}

// ---------- kernel 1: per-object best-anchor PARTIAL argmax (16 chunks) ----------
__global__ __launch_bounds__(256) void k_obj_part(const float* __restrict__ boxes,
                                                  const float* __restrict__ dboxes,
                                                  float* __restrict__ part_iou,
                                                  int* __restrict__ part_idx,
                                                  int N, int O) {
    int bo = blockIdx.x;
    int c  = blockIdx.y;
    const float* bb = boxes + (size_t)bo * 4;
    float ax0 = bb[0], ay0 = bb[1], ax1 = bb[2], ay1 = bb[3];
    int chunk = (N + CHUNKS - 1) / CHUNKS;
    int n0 = c * chunk;
    int n1 = min(n0 + chunk, N);
    float best = -1.f; int bi = 0x7FFFFFFF;
    for (int n = n0 + threadIdx.x; n < n1; n += 256) {
        float4 d = ((const float4*)dboxes)[n];
        float dx0 = d.x - d.z * 0.5f, dy0 = d.y - d.w * 0.5f;
        float dx1 = d.x + d.z * 0.5f, dy1 = d.y + d.w * 0.5f;
        float iou = iou_xy(ax0, ay0, ax1, ay1, dx0, dy0, dx1, dy1);
        if (iou > best) { best = iou; bi = n; }   // ascending n + strict > = first max
    }
    #pragma unroll
    for (int dd = 1; dd < 64; dd <<= 1) {
        float v2 = __shfl_xor(best, dd); int i2 = __shfl_xor(bi, dd);
        if (v2 > best || (v2 == best && i2 < bi)) { best = v2; bi = i2; }
    }
    __shared__ float sv[4]; __shared__ int si[4];
    int w = threadIdx.x >> 6;
    if ((threadIdx.x & 63) == 0) { sv[w] = best; si[w] = bi; }
    __syncthreads();
    if (threadIdx.x == 0) {
        #pragma unroll
        for (int i = 1; i < 4; ++i)
            if (sv[i] > best || (sv[i] == best && si[i] < bi)) { best = sv[i]; bi = si[i]; }
        part_iou[(size_t)bo * CHUNKS + c] = best;
        part_idx[(size_t)bo * CHUNKS + c] = bi;
    }
}

// ---------- kernel 2: reduce the 16 partials per (b,o) ---------------------------
__global__ void k_obj_reduce(const float* __restrict__ part_iou,
                             const int* __restrict__ part_idx,
                             int* __restrict__ defbox_object, int BO) {
    int bo = blockIdx.x * blockDim.x + threadIdx.x;
    if (bo >= BO) return;
    float best = -1.f; int bi = 0x7FFFFFFF;
    #pragma unroll
    for (int c = 0; c < CHUNKS; ++c) {
        float v = part_iou[(size_t)bo * CHUNKS + c];
        int  i = part_idx[(size_t)bo * CHUNKS + c];
        if (v > best || (v == best && i < bi)) { best = v; bi = i; }
    }
    defbox_object[bo] = bi;
}

// ---------- kernel 3: persistent dbuf pipeline (7 blocks/CU): CE+match+loc -------
// TILEA=32 -> dbuf LDS 20.7 KB -> 7 blocks/CU, 1760 blocks resident. Per tile:
// async stage(t+1) -> phase2(t) on all 4 waves (8 lanes/anchor) -> barrier.
// 2.3x the in-flight HBM streams of the R9 version.
template<int OT>
__global__ __launch_bounds__(256)
void k_conf(const float* __restrict__ locs_pred,
            const float* __restrict__ cls,
            const float* __restrict__ boxes,
            const int* __restrict__ labels,
            const float* __restrict__ dboxes,
            const int* __restrict__ dbo_g,
            float* __restrict__ vneg,
            int* __restrict__ n_pos,
            float* __restrict__ loc_sum,
            float* __restrict__ pos_conf,
            int N, int O_rt, int bpb, int tilesPerBatch) {
    const int O = OT ? OT : O_rt;
    __shared__ __align__(16) float sm[2][TILEA * CCLS];   // 2 x 10.4 KB
    __shared__ float sbb[64];
    __shared__ int slab[16], sdbo[16];
    __shared__ float swl[4], swp[4];
    __shared__ int swc[4];
    const int tid = threadIdx.x;
    const int b  = blockIdx.x / bpb;
    const int t0 = (blockIdx.x % bpb) * TPB;
    const int tEnd = min(t0 + TPB, tilesPerBatch);

    if (tid < O * 4) sbb[tid] = boxes[(size_t)b * O * 4 + tid];
    else if (tid < O * 5) slab[tid - O * 4] = labels[(size_t)b * O + tid - O * 4];
    else if (tid < O * 6) sdbo[tid - O * 5] = dbo_g[(size_t)b * O + tid - O * 5];

    const int lane = tid & 63, w = tid >> 6;
    const int al = lane >> 3, q = lane & 7;            // 8 lanes per anchor

    auto stage = [&](int buf, int t) {
        int a0 = t * TILEA;
        int valid = min(TILEA, N - a0);
        const float4* g4 = (const float4*)(cls + ((size_t)b * N + a0) * CCLS);
        float4* s4 = (float4*)sm[buf];
        if (valid == TILEA) {
            int base = w * 162;                        // 648 float4 / 4 waves
            gload16(g4 + base + lane, s4 + base);
            gload16(g4 + base + 64 + lane, s4 + base + 64);
            if (lane < 34) gload16(g4 + base + 128 + lane, s4 + base + 128);
        } else {
            int len = valid * CCLS;
            const float* g = (const float*)g4;
            for (int i = tid; i < len; i += 256) sm[buf][i] = g[i];
        }
    };

    float pc = 0.f, ls = 0.f; int cnt = 0;

    auto phase2 = [&](int buf, int t) {
        int a0 = t * TILEA;
        int valid = min(TILEA, N - a0);
        int a = w * 8 + al;                            // anchor within tile
        const float* row = &sm[buf][a * CCLS];
        float s = 0.f;
        bool act = a < valid;
        if (act) {
            int c0 = q * 10;
            #pragma unroll
            for (int i = 0; i < 10; ++i) s += __expf(row[c0 + i]);
            if (q == 7) s += __expf(row[80]);
        }
        s += __shfl_xor(s, 1);                         // combine 8 chunks
        s += __shfl_xor(s, 2);
        s += __shfl_xor(s, 4);
        if (act && q == 0) {
            int n = a0 + a;
            float4 d = ((const float4*)dboxes)[n];
            float dx0 = d.x - d.z * 0.5f, dy0 = d.y - d.w * 0.5f;
            float dx1 = d.x + d.z * 0.5f, dy1 = d.y + d.w * 0.5f;
            float best = -1.f; int sel = 0;
            #pragma unroll
            for (int o = 0; o < O; ++o) {
                float iou = iou_xy(sbb[o*4], sbb[o*4+1], sbb[o*4+2], sbb[o*4+3],
                                   dx0, dy0, dx1, dy1);
                if (iou > best) { best = iou; sel = o; }   // first-max
            }
            bool forced = false;
            #pragma unroll
            for (int o = 0; o < O; ++o)
                if (sdbo[o] == n) { sel = o; forced = true; }   // last-wins
            float iou_eff = forced ? 1.0f : best;
            int lbl = (iou_eff < THRESH) ? 0 : slab[sel];
            float conf = __logf(s) - row[lbl];
            bool pos = (lbl != 0);
            size_t idx = (size_t)b * N + n;
            vneg[idx] = pos ? 0.f : conf;
            if (pos) {
                pc += conf; cnt++;
                float bx0 = sbb[sel*4], by0 = sbb[sel*4+1];
                float bx1 = sbb[sel*4+2], by1 = sbb[sel*4+3];
                float bcx = (bx0 + bx1) * 0.5f, bcy = (by0 + by1) * 0.5f;
                float bw = bx1 - bx0, bh = by1 - by0;
                float t0f = (bcx - d.x) / (d.z / 10.0f + EPSf);
                float t1f = (bcy - d.y) / (d.w / 10.0f + EPSf);
                float t2f = __logf(bw / d.z + EPSf) * 5.0f;
                float t3f = __logf(bh / d.w + EPSf) * 5.0f;
                float4 p = ((const float4*)locs_pred)[idx];
                float dd;
                dd = fabsf(p.x - t0f); ls += (dd < 1.f) ? 0.5f*dd*dd : dd - 0.5f;
                dd = fabsf(p.y - t1f); ls += (dd < 1.f) ? 0.5f*dd*dd : dd - 0.5f;
                dd = fabsf(p.z - t2f); ls += (dd < 1.f) ? 0.5f*dd*dd : dd - 0.5f;
                dd = fabsf(p.w - t3f); ls += (dd < 1.f) ? 0.5f*dd*dd : dd - 0.5f;
            }
        }
    };

    if (t0 < tEnd) stage(0, t0);
    __syncthreads();
    int cur = 0;
    for (int t = t0; t < tEnd; ++t) {
        if (t + 1 < tEnd) stage(cur ^ 1, t + 1);   // async, overlaps phase2
        phase2(cur, t);
        __syncthreads();                           // drains vmcnt + lgkm
        cur ^= 1;
    }

    #pragma unroll
    for (int dd = 1; dd < 64; dd <<= 1) {
        pc  += __shfl_xor(pc, dd);
        ls  += __shfl_xor(ls, dd);
        cnt += __shfl_xor(cnt, dd);
    }
    if (lane == 0) { swp[w] = pc; swl[w] = ls; swc[w] = cnt; }
    __syncthreads();
    if (tid == 0) {
        float P = swp[0] + swp[1] + swp[2] + swp[3];
        float L = swl[0] + swl[1] + swl[2] + swl[3];
        int   C = swc[0] + swc[1] + swc[2] + swc[3];
        if (C) {
            atomicAdd(&n_pos[b], C);
            atomicAdd(loc_sum, L);
            atomicAdd(pos_conf, P);
        }
    }
}

// ---------- select pipeline: chunked LDS-atomic hists, exact top-k ---------------
template<int WORDS>
__device__ __forceinline__ int2 wave_sel(const int* __restrict__ hist, int k) {
    int lane = threadIdx.x & 63;
    int vals[WORDS];
    #pragma unroll
    for (int j = 0; j < WORDS; ++j) vals[j] = hist[j * 64 + lane];
    int cum = 0, bin = 0, krem = 1; bool found = false;
    #pragma unroll
    for (int j = WORDS - 1; j >= 0; --j) {
        int val = vals[j];
        int s = val;                                   // descending suffix-sum
        #pragma unroll
        for (int d = 1; d < 64; d <<= 1) {
            int t = __shfl_down(s, d);
            if (lane + d < 64) s += t;
        }
        int total = __shfl(s, 0);
        if (!found && cum + total >= k) {
            unsigned long long mask = __ballot(cum + s >= k);
            int bl = 63 - __builtin_clzll(mask);
            int sB = __shfl(s, bl);
            int vB = __shfl(val, bl);
            bin = j * 64 + bl;
            krem = k - (cum + sB - vB);
            found = true;
        }
        cum += total;
    }
    return make_int2(bin, krem);
}

__global__ __launch_bounds__(256) void kh1(const float* __restrict__ vneg,
                                           int* __restrict__ ghist1, int N) {
    int b = blockIdx.x, c = blockIdx.y;
    __shared__ int h[2048];
    for (int i = threadIdx.x; i < 2048; i += 256) h[i] = 0;
    __syncthreads();
    const float4* v4 = (const float4*)(vneg + (size_t)b * N);
    int nv = N >> 2;
    int ch = (nv + NCH2 - 1) / NCH2;
    int i0 = c * ch, i1 = min(i0 + ch, nv);
    for (int i = i0 + threadIdx.x; i < i1; i += 256) {
        float4 x = v4[i];
        atomicAdd(&h[__float_as_uint(x.x) >> 20], 1);
        atomicAdd(&h[__float_as_uint(x.y) >> 20], 1);
        atomicAdd(&h[__float_as_uint(x.z) >> 20], 1);
        atomicAdd(&h[__float_as_uint(x.w) >> 20], 1);
    }
    __syncthreads();
    int* g = ghist1 + b * 2048;
    for (int i = threadIdx.x; i < 2048; i += 256)
        if (h[i]) atomicAdd(&g[i], h[i]);
}

__global__ __launch_bounds__(256) void kh2(const float* __restrict__ vneg,
                                           const int* __restrict__ n_pos,
                                           const int* __restrict__ ghist1,
                                           int* __restrict__ ghist2, int N) {
    int b = blockIdx.x, c = blockIdx.y;
    int k = min(NEG_POSK * n_pos[b], N);
    __shared__ int sB1;
    __shared__ int h[2048];
    for (int i = threadIdx.x; i < 2048; i += 256) h[i] = 0;
    if (threadIdx.x < 64) {
        int2 r = wave_sel<32>(ghist1 + b * 2048, k);
        if (threadIdx.x == 0) sB1 = r.x;
    }
    __syncthreads();
    unsigned B1 = (unsigned)sB1;
    const float4* v4 = (const float4*)(vneg + (size_t)b * N);
    int nv = N >> 2;
    int ch = (nv + NCH2 - 1) / NCH2;
    int i0 = c * ch, i1 = min(i0 + ch, nv);
    for (int i = i0 + threadIdx.x; i < i1; i += 256) {
        float4 x = v4[i];
        unsigned ux = __float_as_uint(x.x), uy = __float_as_uint(x.y);
        unsigned uz = __float_as_uint(x.z), uw = __float_as_uint(x.w);
        if ((ux >> 20) == B1) atomicAdd(&h[(ux >> 9) & 0x7FF], 1);
        if ((uy >> 20) == B1) atomicAdd(&h[(uy >> 9) & 0x7FF], 1);
        if ((uz >> 20) == B1) atomicAdd(&h[(uz >> 9) & 0x7FF], 1);
        if ((uw >> 20) == B1) atomicAdd(&h[(uw >> 9) & 0x7FF], 1);
    }
    __syncthreads();
    int* g = ghist2 + b * 2048;
    for (int i = threadIdx.x; i < 2048; i += 256)
        if (h[i]) atomicAdd(&g[i], h[i]);
}

__global__ __launch_bounds__(256) void kh3(const float* __restrict__ vneg,
                                           const int* __restrict__ n_pos,
                                           const int* __restrict__ ghist1,
                                           const int* __restrict__ ghist2,
                                           int* __restrict__ ghist3, int N) {
    int b = blockIdx.x, c = blockIdx.y;
    int k = min(NEG_POSK * n_pos[b], N);
    __shared__ int sPre;
    __shared__ int h[512];
    for (int i = threadIdx.x; i < 512; i += 256) h[i] = 0;
    if (threadIdx.x < 64) {
        int2 r1 = wave_sel<32>(ghist1 + b * 2048, k);
        int2 r2 = wave_sel<32>(ghist2 + b * 2048, r1.y);
        if (threadIdx.x == 0) sPre = (r1.x << 11) | r2.x;
    }
    __syncthreads();
    unsigned pre = (unsigned)sPre;
    const float4* v4 = (const float4*)(vneg + (size_t)b * N);
    int nv = N >> 2;
    int ch = (nv + NCH2 - 1) / NCH2;
    int i0 = c * ch, i1 = min(i0 + ch, nv);
    for (int i = i0 + threadIdx.x; i < i1; i += 256) {
        float4 x = v4[i];
        unsigned ux = __float_as_uint(x.x), uy = __float_as_uint(x.y);
        unsigned uz = __float_as_uint(x.z), uw = __float_as_uint(x.w);
        if ((ux >> 9) == pre) atomicAdd(&h[ux & 0x1FF], 1);
        if ((uy >> 9) == pre) atomicAdd(&h[uy & 0x1FF], 1);
        if ((uz >> 9) == pre) atomicAdd(&h[uz & 0x1FF], 1);
        if ((uw >> 9) == pre) atomicAdd(&h[uw & 0x1FF], 1);
    }
    __syncthreads();
    int* g = ghist3 + b * 512;
    for (int i = threadIdx.x; i < 512; i += 256)
        if (h[i]) atomicAdd(&g[i], h[i]);
}

__global__ __launch_bounds__(256) void kscan(const float* __restrict__ vneg,
                                             const int* __restrict__ n_pos,
                                             const int* __restrict__ ghist1,
                                             const int* __restrict__ ghist2,
                                             const int* __restrict__ ghist3,
                                             float* __restrict__ hard_s,
                                             int* __restrict__ hard_c,
                                             float* __restrict__ tau_arr, int N) {
    int b = blockIdx.x, c = blockIdx.y;
    int k = min(NEG_POSK * n_pos[b], N);
    __shared__ float stau;
    if (threadIdx.x < 64) {
        int2 r1 = wave_sel<32>(ghist1 + b * 2048, k);
        int2 r2 = wave_sel<32>(ghist2 + b * 2048, r1.y);
        int2 r3 = wave_sel<8>(ghist3 + b * 512, r2.y);
        if (threadIdx.x == 0)
            stau = __uint_as_float(((unsigned)r1.x << 20) | ((unsigned)r2.x << 9)
                                   | (unsigned)r3.x);
    }
    __syncthreads();
    float tau = stau;
    const float4* v4 = (const float4*)(vneg + (size_t)b * N);
    int nv = N >> 2;
    int ch = (nv + NCH2 - 1) / NCH2;
    int i0 = c * ch, i1 = min(i0 + ch, nv);
    float ssum = 0.f; int scnt = 0;
    for (int i = i0 + threadIdx.x; i < i1; i += 256) {
        float4 x = v4[i];
        if (x.x > tau) { ssum += x.x; scnt++; }
        if (x.y > tau) { ssum += x.y; scnt++; }
        if (x.z > tau) { ssum += x.z; scnt++; }
        if (x.w > tau) { ssum += x.w; scnt++; }
    }
    #pragma unroll
    for (int d = 1; d < 64; d <<= 1) {
        ssum += __shfl_xor(ssum, d);
        scnt += __shfl_xor(scnt, d);
    }
    __shared__ float swv[4]; __shared__ int swc[4];
    int w = threadIdx.x >> 6;
    if ((threadIdx.x & 63) == 0) { swv[w] = ssum; swc[w] = scnt; }
    __syncthreads();
    if (threadIdx.x == 0) {
        float S = swv[0] + swv[1] + swv[2] + swv[3];
        int Ct = swc[0] + swc[1] + swc[2] + swc[3];
        if (S != 0.f || Ct != 0) { atomicAdd(&hard_s[b], S); atomicAdd(&hard_c[b], Ct); }
        if (c == 0) tau_arr[b] = stau;
    }
}

// ---------- finalize -------------------------------------------------------------
__global__ void k_final(const int* __restrict__ n_pos,
                        const float* __restrict__ loc_sum,
                        const float* __restrict__ pos_conf,
                        const float* __restrict__ hard_s,
                        const int* __restrict__ hard_c,
                        const float* __restrict__ tau_arr,
                        float* __restrict__ out, int B, int N) {
    if (threadIdx.x == 0 && blockIdx.x == 0) {
        int tot = 0;
        for (int b = 0; b < B; ++b) tot += n_pos[b];
        float np = (float)tot;
        float hard = 0.f;
        for (int b = 0; b < B; ++b) {
            int k = min(NEG_POSK * n_pos[b], N);
            hard += hard_s[b] + (float)(k - hard_c[b]) * tau_arr[b];
        }
        float loc = *loc_sum / (np * 4.0f);
        out[0] = 0.5f * loc + (hard + *pos_conf) / np;
    }
}

extern "C" void kernel_launch(void* const* d_in, const int* in_sizes, int n_in,
                              void* d_out, int out_size, void* d_ws, size_t ws_size,
                              hipStream_t stream) {
    const float* locs_pred = (const float*)d_in[0];
    const float* cls_pred  = (const float*)d_in[1];
    const float* boxes     = (const float*)d_in[2];
    const int*   labels    = (const int*)d_in[3];
    const float* dboxes    = (const float*)d_in[4];

    int N = in_sizes[4] / 4;
    int B = in_sizes[0] / (4 * N);
    int O = in_sizes[3] / B;
    int BO = B * O;

    size_t BN = (size_t)B * N;
    char* ws = (char*)d_ws;
    int*   n_pos    = (int*)ws;                        // B ints (B<=32)
    float* loc_sum  = (float*)(ws + 128);
    float* pos_conf = (float*)(ws + 132);
    float* tau_arr  = (float*)(ws + 192);              // B f32
    float* hard_s   = (float*)(ws + 320);              // B f32
    int*   hard_c   = (int*)(ws + 448);                // B i32
    int*   ghist1   = (int*)(ws + 1024);               // B*2048
    int*   ghist2   = ghist1 + (size_t)B * 2048;       // B*2048
    int*   ghist3   = ghist2 + (size_t)B * 2048;       // B*512
    int*   defbox_object = ghist3 + (size_t)B * 512;   // BO
    float* part_iou = (float*)(defbox_object + BO);    // BO*CHUNKS
    int*   part_idx = (int*)(part_iou + (size_t)BO * CHUNKS);
    float* vneg     = (float*)(part_idx + (size_t)BO * CHUNKS);  // BN f32

    size_t zero_bytes = 1024 + ((size_t)B * 2048 * 2 + (size_t)B * 512) * 4;
    hipMemsetAsync(ws, 0, zero_bytes, stream);

    dim3 gop(BO, CHUNKS);
    k_obj_part<<<gop, 256, 0, stream>>>(boxes, dboxes, part_iou, part_idx, N, O);
    k_obj_reduce<<<(BO + 255) / 256, 256, 0, stream>>>(part_iou, part_idx,
                                                       defbox_object, BO);
    int tilesPerBatch = (N + TILEA - 1) / TILEA;            // 768
    int bpb = (tilesPerBatch + TPB - 1) / TPB;              // 55
    dim3 gc(B * bpb);                                       // 1760 blocks, 7/CU
    if (O == 16)
        k_conf<16><<<gc, 256, 0, stream>>>(locs_pred, cls_pred, boxes, labels, dboxes,
                                           defbox_object, vneg, n_pos, loc_sum,
                                           pos_conf, N, O, bpb, tilesPerBatch);
    else
        k_conf<0><<<gc, 256, 0, stream>>>(locs_pred, cls_pred, boxes, labels, dboxes,
                                          defbox_object, vneg, n_pos, loc_sum,
                                          pos_conf, N, O, bpb, tilesPerBatch);
    dim3 gs(B, NCH2);
    kh1<<<gs, 256, 0, stream>>>(vneg, ghist1, N);
    kh2<<<gs, 256, 0, stream>>>(vneg, n_pos, ghist1, ghist2, N);
    kh3<<<gs, 256, 0, stream>>>(vneg, n_pos, ghist1, ghist2, ghist3, N);
    kscan<<<gs, 256, 0, stream>>>(vneg, n_pos, ghist1, ghist2, ghist3,
                                  hard_s, hard_c, tau_arr, N);
    k_final<<<1, 1, 0, stream>>>(n_pos, loc_sum, pos_conf, hard_s, hard_c, tau_arr,
                                 (float*)d_out, B, N);
}

// Round 11
// 167.667 us; speedup vs baseline: 1.2751x; 1.2751x over previous
//
#include <hip/hip_runtime.h>
#include <math.h>

#define THRESH    0.5f
#define NEG_POSK  3
#define EPSf      1e-6f
#define CCLS      81
#define TILEA     64
#define CHUNKS    16
#define TPB       12      // tiles per block; 384 % 12 == 0 -> every block full
#define NBUF      3

__device__ __forceinline__ float iou_xy(float ax0, float ay0, float ax1, float ay1,
                                        float bx0, float by0, float bx1, float by1) {
    float lx = fmaxf(ax0, bx0), ly = fmaxf(ay0, by0);
    float rx = fminf(ax1, bx1), ry = fminf(ay1, by1);
    float w = fmaxf(rx - lx, 0.f), h = fmaxf(ry - ly, 0.f);
    float inter = w * h;
    float aa = (ax1 - ax0) * (ay1 - ay0);
    float ab = (bx1 - bx0) * (by1 - by0);
    return inter / (aa + ab - inter);
}

__device__ __forceinline__ void gload16(const void* g, void* l) {
    __builtin_amdgcn_global_load_lds(
        (const __attribute__((address_space(1))) void*)g,
        (__attribute__((address_space(3))) void*)l, 16, 0, 0);
}

// ---------- kernel 1: per-object best-anchor PARTIAL argmax (16 chunks) ----------
__global__ __launch_bounds__(256) void k_obj_part(const float* __restrict__ boxes,
                                                  const float* __restrict__ dboxes,
                                                  float* __restrict__ part_iou,
                                                  int* __restrict__ part_idx,
                                                  int N, int O) {
    int bo = blockIdx.x;
    int c  = blockIdx.y;
    const float* bb = boxes + (size_t)bo * 4;
    float ax0 = bb[0], ay0 = bb[1], ax1 = bb[2], ay1 = bb[3];
    int chunk = (N + CHUNKS - 1) / CHUNKS;
    int n0 = c * chunk;
    int n1 = min(n0 + chunk, N);
    float best = -1.f; int bi = 0x7FFFFFFF;
    for (int n = n0 + threadIdx.x; n < n1; n += 256) {
        float4 d = ((const float4*)dboxes)[n];
        float dx0 = d.x - d.z * 0.5f, dy0 = d.y - d.w * 0.5f;
        float dx1 = d.x + d.z * 0.5f, dy1 = d.y + d.w * 0.5f;
        float iou = iou_xy(ax0, ay0, ax1, ay1, dx0, dy0, dx1, dy1);
        if (iou > best) { best = iou; bi = n; }   // ascending n + strict > = first max
    }
    #pragma unroll
    for (int dd = 1; dd < 64; dd <<= 1) {
        float v2 = __shfl_xor(best, dd); int i2 = __shfl_xor(bi, dd);
        if (v2 > best || (v2 == best && i2 < bi)) { best = v2; bi = i2; }
    }
    __shared__ float sv[4]; __shared__ int si[4];
    int w = threadIdx.x >> 6;
    if ((threadIdx.x & 63) == 0) { sv[w] = best; si[w] = bi; }
    __syncthreads();
    if (threadIdx.x == 0) {
        #pragma unroll
        for (int i = 1; i < 4; ++i)
            if (sv[i] > best || (sv[i] == best && si[i] < bi)) { best = sv[i]; bi = si[i]; }
        part_iou[(size_t)bo * CHUNKS + c] = best;
        part_idx[(size_t)bo * CHUNKS + c] = bi;
    }
}

// ---------- kernel 2: reduce the 16 partials per (b,o) ---------------------------
__global__ void k_obj_reduce(const float* __restrict__ part_iou,
                             const int* __restrict__ part_idx,
                             int* __restrict__ defbox_object, int BO) {
    int bo = blockIdx.x * blockDim.x + threadIdx.x;
    if (bo >= BO) return;
    float best = -1.f; int bi = 0x7FFFFFFF;
    #pragma unroll
    for (int c = 0; c < CHUNKS; ++c) {
        float v = part_iou[(size_t)bo * CHUNKS + c];
        int  i = part_idx[(size_t)bo * CHUNKS + c];
        if (v > best || (v == best && i < bi)) { best = v; bi = i; }
    }
    defbox_object[bo] = bi;
}

// ---------- kernel 3: persistent 3-deep counted-vmcnt pipeline -------------------
// Per tile: wait vmcnt(9) [stage(t) done, stage(t+1)+phase2(t-1) stay in flight]
// -> s_barrier -> issue stage(t+2) -> phase2(t). Stage = uniform 6 gload16/wave
// (24 chunks x 54 lanes); phase2 VMEM statically issued (3/wave-group) so the
// counted waits are exact under compiler reordering.
template<int OT>
__global__ __launch_bounds__(256)
void k_conf(const float* __restrict__ locs_pred,
            const float* __restrict__ cls,
            const float* __restrict__ boxes,
            const int* __restrict__ labels,
            const float* __restrict__ dboxes,
            const int* __restrict__ dbo_g,
            float* __restrict__ vneg,
            int* __restrict__ n_pos,
            float* __restrict__ loc_sum,
            float* __restrict__ pos_conf,
            int N, int O_rt, int bpb, int tilesPerBatch, long long totalF4) {
    const int O = OT ? OT : O_rt;
    __shared__ __align__(16) float sm[NBUF][TILEA * CCLS];   // 3 x 20.25 KB
    __shared__ float sbb[64];
    __shared__ int slab[16], sdbo[16];
    __shared__ float swl[4], swp[4];
    __shared__ int swc[4];
    const int tid = threadIdx.x;
    const int b  = blockIdx.x / bpb;
    const int t0 = (blockIdx.x % bpb) * TPB;
    const int tEnd = min(t0 + TPB, tilesPerBatch);

    if (tid < O * 4) sbb[tid] = boxes[(size_t)b * O * 4 + tid];
    else if (tid < O * 5) slab[tid - O * 4] = labels[(size_t)b * O + tid - O * 4];
    else if (tid < O * 6) sdbo[tid - O * 5] = dbo_g[(size_t)b * O + tid - O * 5];

    const int lane = tid & 63, w = tid >> 6;
    const int j = lane & 15, q = lane >> 4;

    auto stage = [&](int buf, int t) {
        long long base4 = (((long long)b * N + (long long)t * TILEA) * CCLS) >> 2;
        const float4* g4 = (const float4*)cls + base4;
        float4* s4 = (float4*)sm[buf];
        long long cap = totalF4 - base4;        // >= 1296 except global-last tile
        if (lane < 54) {                        // exec never 0 -> uniform 6 issues
            #pragma unroll
            for (int k2 = 0; k2 < 6; ++k2) {
                int c = (w * 6 + k2) * 54;      // wave-uniform LDS base
                long long gi = c + lane;        // per-lane global src (clamped)
                if (gi >= cap) gi = cap - 1;
                gload16(g4 + gi, s4 + c);
            }
        }
    };

    float pc = 0.f, ls = 0.f; int cnt = 0;

    auto phase2 = [&](int buf, int t) {
        int a0 = t * TILEA;
        int valid = min(TILEA, N - a0);
        int a = w * 16 + j;                     // anchor within tile (4 lanes each)
        const float* row = &sm[buf][a * CCLS];
        bool act = a < valid;
        float s = 0.f;
        if (act) {
            int c0 = q * 20;
            #pragma unroll
            for (int i = 0; i < 20; ++i) s += __expf(row[c0 + i]);
            if (q == 3) s += __expf(row[80]);
        }
        s += __shfl_xor(s, 16);
        s += __shfl_xor(s, 32);
        if (act && q == 0) {                    // 16 lanes/wave, exec!=0 on full tiles
            int n = a0 + a;
            size_t idx = (size_t)b * N + n;
            float4 d = ((const float4*)dboxes)[n];          // static VMEM #1
            float4 p = ((const float4*)locs_pred)[idx];     // static VMEM #2 (hoisted)
            float dx0 = d.x - d.z * 0.5f, dy0 = d.y - d.w * 0.5f;
            float dx1 = d.x + d.z * 0.5f, dy1 = d.y + d.w * 0.5f;
            float best = -1.f; int sel = 0;
            #pragma unroll
            for (int o = 0; o < O; ++o) {
                float iou = iou_xy(sbb[o*4], sbb[o*4+1], sbb[o*4+2], sbb[o*4+3],
                                   dx0, dy0, dx1, dy1);
                if (iou > best) { best = iou; sel = o; }    // first-max
            }
            bool forced = false;
            #pragma unroll
            for (int o = 0; o < O; ++o)
                if (sdbo[o] == n) { sel = o; forced = true; }   // last-wins
            float iou_eff = forced ? 1.0f : best;
            int lbl = (iou_eff < THRESH) ? 0 : slab[sel];
            float conf = __logf(s) - row[lbl];
            bool pos = (lbl != 0);
            vneg[idx] = pos ? 0.f : conf;                   // static VMEM #3
            if (pos) {                                      // VALU-only from here
                pc += conf; cnt++;
                float bx0 = sbb[sel*4], by0 = sbb[sel*4+1];
                float bx1 = sbb[sel*4+2], by1 = sbb[sel*4+3];
                float bcx = (bx0 + bx1) * 0.5f, bcy = (by0 + by1) * 0.5f;
                float bw = bx1 - bx0, bh = by1 - by0;
                float t0f = (bcx - d.x) / (d.z / 10.0f + EPSf);
                float t1f = (bcy - d.y) / (d.w / 10.0f + EPSf);
                float t2f = __logf(bw / d.z + EPSf) * 5.0f;
                float t3f = __logf(bh / d.w + EPSf) * 5.0f;
                float dd;
                dd = fabsf(p.x - t0f); ls += (dd < 1.f) ? 0.5f*dd*dd : dd - 0.5f;
                dd = fabsf(p.y - t1f); ls += (dd < 1.f) ? 0.5f*dd*dd : dd - 0.5f;
                dd = fabsf(p.z - t2f); ls += (dd < 1.f) ? 0.5f*dd*dd : dd - 0.5f;
                dd = fabsf(p.w - t3f); ls += (dd < 1.f) ? 0.5f*dd*dd : dd - 0.5f;
            }
        }
    };

    // prologue: 2 stages in flight
    stage(0, t0);
    stage(1, min(t0 + 1, tEnd - 1));
    for (int t = t0; t < tEnd; ++t) {
        int it = t - t0;
        if (it == 0)
            asm volatile("s_waitcnt vmcnt(6) lgkmcnt(0)" ::: "memory");
        else
            asm volatile("s_waitcnt vmcnt(9)" ::: "memory");
        __builtin_amdgcn_s_barrier();
        __builtin_amdgcn_sched_barrier(0);
        stage((it + 2) % NBUF, min(t + 2, tEnd - 1));   // dummy re-stage past end
        phase2(it % NBUF, t);
    }

    #pragma unroll
    for (int dd = 1; dd < 64; dd <<= 1) {
        pc  += __shfl_xor(pc, dd);
        ls  += __shfl_xor(ls, dd);
        cnt += __shfl_xor(cnt, dd);
    }
    if (lane == 0) { swp[w] = pc; swl[w] = ls; swc[w] = cnt; }
    __syncthreads();                        // full drain (incl. dummy stages)
    if (tid == 0) {
        float P = swp[0] + swp[1] + swp[2] + swp[3];
        float L = swl[0] + swl[1] + swl[2] + swl[3];
        int   C = swc[0] + swc[1] + swc[2] + swc[3];
        if (C) {
            atomicAdd(&n_pos[b], C);
            atomicAdd(loc_sum, L);
            atomicAdd(pos_conf, P);
        }
    }
}

// ---------- kernel 4: exact top-k sum (plain-LDS-atomic version) -----------------
__device__ void wave_select(const int* hist, int nbins, int k, int* out_bin, int* out_k) {
    int lane = threadIdx.x & 63;
    int cum = 0;
    for (int c = nbins / 64 - 1; c >= 0; --c) {
        int val = hist[c * 64 + lane];
        int s = val;                           // descending suffix-sum within chunk
        for (int d = 1; d < 64; d <<= 1) {
            int t = __shfl_down(s, d);
            if (lane + d < 64) s += t;
        }
        int total = __shfl(s, 0);
        if (cum + total >= k) {
            unsigned long long mask = __ballot(cum + s >= k);
            int bl = 63 - __builtin_clzll(mask);
            int sB = __shfl(s, bl);
            int vB = __shfl(val, bl);
            if (lane == 0) {
                *out_bin = c * 64 + bl;
                *out_k = k - (cum + sB - vB);
            }
            return;
        }
        cum += total;
    }
    if (lane == 0) { *out_bin = 0; *out_k = 1; }
}

__global__ __launch_bounds__(1024) void k_select(const float* __restrict__ vneg,
                                                 const int* __restrict__ n_pos,
                                                 float* __restrict__ hard_sum,
                                                 int B, int N) {
    int b = blockIdx.x;
    const float* v = vneg + (size_t)b * N;
    __shared__ int hist[2048];
    __shared__ int bcast_bin, bcast_k;
    __shared__ float swv[16];
    __shared__ int swc[16];
    int np = n_pos[b];
    long long kk = (long long)NEG_POSK * np;
    if (kk > N) kk = N;
    int k = (int)kk;
    if (k <= 0) return;   // uniform across block
    int tid = threadIdx.x;

    for (int i = tid; i < 2048; i += 1024) hist[i] = 0;
    __syncthreads();
    for (int n = tid; n < N; n += 1024) {
        unsigned u = __float_as_uint(v[n]);
        atomicAdd(&hist[u >> 20], 1);
    }
    __syncthreads();
    if (tid < 64) wave_select(hist, 2048, k, &bcast_bin, &bcast_k);
    __syncthreads();
    int B1 = bcast_bin, k2 = bcast_k;

    for (int i = tid; i < 2048; i += 1024) hist[i] = 0;
    __syncthreads();
    for (int n = tid; n < N; n += 1024) {
        unsigned u = __float_as_uint(v[n]);
        if ((int)(u >> 20) == B1) atomicAdd(&hist[(u >> 9) & 0x7FF], 1);
    }
    __syncthreads();
    if (tid < 64) wave_select(hist, 2048, k2, &bcast_bin, &bcast_k);
    __syncthreads();
    int B2 = bcast_bin, k3 = bcast_k;
    unsigned pre = ((unsigned)B1 << 11) | (unsigned)B2;

    for (int i = tid; i < 512; i += 1024) hist[i] = 0;
    __syncthreads();
    for (int n = tid; n < N; n += 1024) {
        unsigned u = __float_as_uint(v[n]);
        if ((u >> 9) == pre) atomicAdd(&hist[u & 0x1FF], 1);
    }
    __syncthreads();
    if (tid < 64) wave_select(hist, 512, k3, &bcast_bin, &bcast_k);
    __syncthreads();
    unsigned tau_bits = (pre << 9) | (unsigned)bcast_bin;
    float tau = __uint_as_float(tau_bits);

    float ssum = 0.f; int scnt = 0;
    for (int n = tid; n < N; n += 1024) {
        float x = v[n];
        if (x > tau) { ssum += x; scnt++; }
    }
    for (int d = 1; d < 64; d <<= 1) {
        ssum += __shfl_xor(ssum, d);
        scnt += __shfl_xor(scnt, d);
    }
    int w = tid >> 6;
    if ((tid & 63) == 0) { swv[w] = ssum; swc[w] = scnt; }
    __syncthreads();
    if (tid == 0) {
        float S = 0.f; int Ct = 0;
        for (int i = 0; i < 16; ++i) { S += swv[i]; Ct += swc[i]; }
        float hb = S + (float)(k - Ct) * tau;
        atomicAdd(hard_sum, hb);
    }
}

// ---------- kernel 5: finalize ---------------------------------------------------
__global__ void k_final(const int* __restrict__ n_pos,
                        const float* __restrict__ loc_sum,
                        const float* __restrict__ pos_conf,
                        const float* __restrict__ hard_sum,
                        float* __restrict__ out, int B) {
    if (threadIdx.x == 0 && blockIdx.x == 0) {
        int tot = 0;
        for (int b = 0; b < B; ++b) tot += n_pos[b];
        float np = (float)tot;
        float loc = *loc_sum / (np * 4.0f);
        float conf = (*hard_sum + *pos_conf) / np;
        out[0] = 0.5f * loc + conf;
    }
}

extern "C" void kernel_launch(void* const* d_in, const int* in_sizes, int n_in,
                              void* d_out, int out_size, void* d_ws, size_t ws_size,
                              hipStream_t stream) {
    const float* locs_pred = (const float*)d_in[0];
    const float* cls_pred  = (const float*)d_in[1];
    const float* boxes     = (const float*)d_in[2];
    const int*   labels    = (const int*)d_in[3];
    const float* dboxes    = (const float*)d_in[4];

    int N = in_sizes[4] / 4;
    int B = in_sizes[0] / (4 * N);
    int O = in_sizes[3] / B;
    int BO = B * O;

    size_t BN = (size_t)B * N;
    char* ws = (char*)d_ws;
    int*   n_pos    = (int*)ws;                        // B ints
    float* loc_sum  = (float*)(ws + 128);
    float* pos_conf = (float*)(ws + 132);
    float* hard_sum = (float*)(ws + 136);
    float* vneg     = (float*)(ws + 256);              // BN f32
    int*   defbox_object = (int*)(ws + 256 + BN * 4);  // BO i32
    float* part_iou = (float*)(ws + 256 + BN * 4 + (size_t)BO * 4);
    int*   part_idx = (int*)(part_iou + (size_t)BO * CHUNKS);

    hipMemsetAsync(ws, 0, 256, stream);

    dim3 gop(BO, CHUNKS);
    k_obj_part<<<gop, 256, 0, stream>>>(boxes, dboxes, part_iou, part_idx, N, O);
    k_obj_reduce<<<(BO + 255) / 256, 256, 0, stream>>>(part_iou, part_idx,
                                                       defbox_object, BO);
    int tilesPerBatch = (N + TILEA - 1) / TILEA;            // 384
    int bpb = (tilesPerBatch + TPB - 1) / TPB;              // 32
    long long totalF4 = ((long long)B * N * CCLS) >> 2;
    dim3 gc(B * bpb);                                       // 1024 blocks, 2/CU
    if (O == 16)
        k_conf<16><<<gc, 256, 0, stream>>>(locs_pred, cls_pred, boxes, labels, dboxes,
                                           defbox_object, vneg, n_pos, loc_sum,
                                           pos_conf, N, O, bpb, tilesPerBatch, totalF4);
    else
        k_conf<0><<<gc, 256, 0, stream>>>(locs_pred, cls_pred, boxes, labels, dboxes,
                                          defbox_object, vneg, n_pos, loc_sum,
                                          pos_conf, N, O, bpb, tilesPerBatch, totalF4);
    k_select<<<B, 1024, 0, stream>>>(vneg, n_pos, hard_sum, B, N);
    k_final<<<1, 1, 0, stream>>>(n_pos, loc_sum, pos_conf, hard_sum, (float*)d_out, B);
}

// Round 12
// 127.882 us; speedup vs baseline: 1.6719x; 1.3111x over previous
//
#include <hip/hip_runtime.h>
#include <math.h>

#define THRESH    0.5f
#define NEG_POSK  3
#define EPSf      1e-6f
#define CCLS      81
#define TILEA     64
#define CHUNKS    16
#define TPB       16      // tiles per block (k_conf)

__device__ __forceinline__ float iou_xy(float ax0, float ay0, float ax1, float ay1,
                                        float bx0, float by0, float bx1, float by1) {
    float lx = fmaxf(ax0, bx0), ly = fmaxf(ay0, by0);
    float rx = fminf(ax1, bx1), ry = fminf(ay1, by1);
    float w = fmaxf(rx - lx, 0.f), h = fmaxf(ry - ly, 0.f);
    float inter = w * h;
    float aa = (ax1 - ax0) * (ay1 - ay0);
    float ab = (bx1 - bx0) * (by1 - by0);
    return inter / (aa + ab - inter);
}

__device__ __forceinline__ void gload16(const void* g, void* l) {
    __builtin_amdgcn_global_load_lds(
        (const __attribute__((address_space(1))) void*)g,
        (__attribute__((address_space(3))) void*)l, 16, 0, 0);
}

// ---------- kernel 1: per-object best-anchor PARTIAL argmax (16 chunks) ----------
__global__ __launch_bounds__(256) void k_obj_part(const float* __restrict__ boxes,
                                                  const float* __restrict__ dboxes,
                                                  float* __restrict__ part_iou,
                                                  int* __restrict__ part_idx,
                                                  int N, int O) {
    int bo = blockIdx.x;
    int c  = blockIdx.y;
    const float* bb = boxes + (size_t)bo * 4;
    float ax0 = bb[0], ay0 = bb[1], ax1 = bb[2], ay1 = bb[3];
    int chunk = (N + CHUNKS - 1) / CHUNKS;
    int n0 = c * chunk;
    int n1 = min(n0 + chunk, N);
    float best = -1.f; int bi = 0x7FFFFFFF;
    for (int n = n0 + threadIdx.x; n < n1; n += 256) {
        float4 d = ((const float4*)dboxes)[n];
        float dx0 = d.x - d.z * 0.5f, dy0 = d.y - d.w * 0.5f;
        float dx1 = d.x + d.z * 0.5f, dy1 = d.y + d.w * 0.5f;
        float iou = iou_xy(ax0, ay0, ax1, ay1, dx0, dy0, dx1, dy1);
        if (iou > best) { best = iou; bi = n; }   // ascending n + strict > = first max
    }
    #pragma unroll
    for (int dd = 1; dd < 64; dd <<= 1) {
        float v2 = __shfl_xor(best, dd); int i2 = __shfl_xor(bi, dd);
        if (v2 > best || (v2 == best && i2 < bi)) { best = v2; bi = i2; }
    }
    __shared__ float sv[4]; __shared__ int si[4];
    int w = threadIdx.x >> 6;
    if ((threadIdx.x & 63) == 0) { sv[w] = best; si[w] = bi; }
    __syncthreads();
    if (threadIdx.x == 0) {
        #pragma unroll
        for (int i = 1; i < 4; ++i)
            if (sv[i] > best || (sv[i] == best && si[i] < bi)) { best = sv[i]; bi = si[i]; }
        part_iou[(size_t)bo * CHUNKS + c] = best;
        part_idx[(size_t)bo * CHUNKS + c] = bi;
    }
}

// ---------- kernel 2: reduce the 16 partials per (b,o) ---------------------------
__global__ void k_obj_reduce(const float* __restrict__ part_iou,
                             const int* __restrict__ part_idx,
                             int* __restrict__ defbox_object, int BO) {
    int bo = blockIdx.x * blockDim.x + threadIdx.x;
    if (bo >= BO) return;
    float best = -1.f; int bi = 0x7FFFFFFF;
    #pragma unroll
    for (int c = 0; c < CHUNKS; ++c) {
        float v = part_iou[(size_t)bo * CHUNKS + c];
        int  i = part_idx[(size_t)bo * CHUNKS + c];
        if (v > best || (v == best && i < bi)) { best = v; bi = i; }
    }
    defbox_object[bo] = bi;
}

// ---------- kernel 3: persistent dbuf pipeline (R9 structure) --------------------
// phase2 rewritten: match distributed over all 4 lanes/anchor (4 objects each),
// division-free IoU argmax (cross-multiplied compare), per-lane object data
// hoisted to registers outside the tile loop.
template<int OT>
__global__ __launch_bounds__(256)
void k_conf(const float* __restrict__ locs_pred,
            const float* __restrict__ cls,
            const float* __restrict__ boxes,
            const int* __restrict__ labels,
            const float* __restrict__ dboxes,
            const int* __restrict__ dbo_g,
            float* __restrict__ vneg,
            int* __restrict__ n_pos,
            float* __restrict__ loc_sum,
            float* __restrict__ pos_conf,
            int N, int O_rt, int bpb, int tilesPerBatch) {
    const int O = OT ? OT : O_rt;
    __shared__ __align__(16) float sm[2][TILEA * CCLS];   // 2 x 20.7 KB
    __shared__ float sbb[64];
    __shared__ int slab[16], sdbo[16];
    __shared__ float swl[4], swp[4];
    __shared__ int swc[4];
    const int tid = threadIdx.x;
    const int b  = blockIdx.x / bpb;
    const int t0 = (blockIdx.x % bpb) * TPB;
    const int tEnd = min(t0 + TPB, tilesPerBatch);

    if (tid < O * 4) sbb[tid] = boxes[(size_t)b * O * 4 + tid];
    else if (tid < O * 5) slab[tid - O * 4] = labels[(size_t)b * O + tid - O * 4];
    else if (tid < O * 6) sdbo[tid - O * 5] = dbo_g[(size_t)b * O + tid - O * 5];

    const int lane = tid & 63, w = tid >> 6;
    const int j = lane & 15, q = lane >> 4;

    auto stage = [&](int buf, int t) {
        int a0 = t * TILEA;
        int valid = min(TILEA, N - a0);
        const float4* g4 = (const float4*)(cls + ((size_t)b * N + a0) * CCLS);
        float4* s4 = (float4*)sm[buf];
        if (valid == TILEA) {
            #pragma unroll
            for (int k2 = 0; k2 < 5; ++k2) {
                int i4 = w * 64 + k2 * 256;            // wave-uniform LDS base
                gload16(g4 + i4 + lane, s4 + i4);
            }
            if (tid < 16) gload16(g4 + 1280 + tid, s4 + 1280);
        } else {
            int len = valid * CCLS;
            const float* g = (const float*)g4;
            for (int i = tid; i < len; i += 256) sm[buf][i] = g[i];
        }
    };

    stage(0, t0);
    __syncthreads();

    // hoist this lane's 4 objects (q*4 .. q*4+3) into registers
    float obx0[4], oby0[4], obx1[4], oby1[4], oarea[4];
    int odbo[4];
    #pragma unroll
    for (int oo = 0; oo < 4; ++oo) {
        int o = q * 4 + oo;
        obx0[oo] = sbb[o*4];   oby0[oo] = sbb[o*4+1];
        obx1[oo] = sbb[o*4+2]; oby1[oo] = sbb[o*4+3];
        oarea[oo] = (obx1[oo] - obx0[oo]) * (oby1[oo] - oby0[oo]);
        odbo[oo] = sdbo[o];
    }

    float pc = 0.f, ls = 0.f; int cnt = 0;

    auto phase2 = [&](int buf, int t) {
        int a0 = t * TILEA;
        int valid = min(TILEA, N - a0);
        int a = w * 16 + j;                            // anchor; 4 lanes (q) each
        bool act = a < valid;
        int n = a0 + a;
        int nc = min(n, N - 1);
        float4 d = ((const float4*)dboxes)[nc];
        float dx0 = d.x - d.z * 0.5f, dy0 = d.y - d.w * 0.5f;
        float dx1 = d.x + d.z * 0.5f, dy1 = d.y + d.w * 0.5f;
        float areaD = d.z * d.w;
        // division-free first-max argmax over this lane's 4 objects
        float bi = -1.f, bu = 1.f; int bsel = q * 4;
        int fs = -1;
        #pragma unroll
        for (int oo = 0; oo < 4; ++oo) {
            float lx = fmaxf(obx0[oo], dx0), ly = fmaxf(oby0[oo], dy0);
            float rx = fminf(obx1[oo], dx1), ry = fminf(oby1[oo], dy1);
            float ww = fmaxf(rx - lx, 0.f), hh = fmaxf(ry - ly, 0.f);
            float inter = ww * hh;
            float uni = oarea[oo] + areaD - inter;
            float c1 = inter * bu, c2 = bi * uni;
            if (c1 > c2) { bi = inter; bu = uni; bsel = q * 4 + oo; }  // strict >
            if (odbo[oo] == n) fs = q * 4 + oo;        // last-wins within group
        }
        // combine across the 4 q-groups (first-max: equal -> lower sel)
        #pragma unroll
        for (int dd = 16; dd < 64; dd <<= 1) {
            float oi = __shfl_xor(bi, dd), ou = __shfl_xor(bu, dd);
            int os = __shfl_xor(bsel, dd);
            int of = __shfl_xor(fs, dd);
            float c1 = oi * bu, c2 = bi * ou;
            if (c1 > c2 || (c1 == c2 && os < bsel)) { bi = oi; bu = ou; bsel = os; }
            fs = max(fs, of);                          // last-wins overall
        }
        // exp quarter-sum (raw logits staged)
        const float* row = &sm[buf][a * CCLS];
        float s = 0.f;
        if (act) {
            int c0 = q * 20;
            #pragma unroll
            for (int i = 0; i < 20; ++i) s += __expf(row[c0 + i]);
            if (q == 3) s += __expf(row[80]);
        }
        s += __shfl_xor(s, 16);
        s += __shfl_xor(s, 32);
        if (act && q == 0) {
            bool forced = fs >= 0;
            int sel = forced ? fs : bsel;
            bool meets = forced || (bi >= 0.5f * bu);  // iou >= 0.5 (union > 0)
            int lbl = meets ? slab[sel] : 0;
            float conf = __logf(s) - row[lbl];
            bool pos = (lbl != 0);
            size_t idx = (size_t)b * N + n;
            vneg[idx] = pos ? 0.f : conf;
            if (pos) {
                pc += conf; cnt++;
                float bx0 = sbb[sel*4], by0 = sbb[sel*4+1];
                float bx1 = sbb[sel*4+2], by1 = sbb[sel*4+3];
                float bcx = (bx0 + bx1) * 0.5f, bcy = (by0 + by1) * 0.5f;
                float bw = bx1 - bx0, bh = by1 - by0;
                float t0f = (bcx - d.x) / (d.z / 10.0f + EPSf);
                float t1f = (bcy - d.y) / (d.w / 10.0f + EPSf);
                float t2f = __logf(bw / d.z + EPSf) * 5.0f;
                float t3f = __logf(bh / d.w + EPSf) * 5.0f;
                float4 p = ((const float4*)locs_pred)[idx];
                float dd;
                dd = fabsf(p.x - t0f); ls += (dd < 1.f) ? 0.5f*dd*dd : dd - 0.5f;
                dd = fabsf(p.y - t1f); ls += (dd < 1.f) ? 0.5f*dd*dd : dd - 0.5f;
                dd = fabsf(p.z - t2f); ls += (dd < 1.f) ? 0.5f*dd*dd : dd - 0.5f;
                dd = fabsf(p.w - t3f); ls += (dd < 1.f) ? 0.5f*dd*dd : dd - 0.5f;
            }
        }
    };

    int cur = 0;
    for (int t = t0; t < tEnd; ++t) {
        if (t + 1 < tEnd) stage(cur ^ 1, t + 1);   // async, overlaps phase2
        phase2(cur, t);
        __syncthreads();                           // drains vmcnt + lgkm
        cur ^= 1;
    }

    #pragma unroll
    for (int dd = 1; dd < 64; dd <<= 1) {
        pc  += __shfl_xor(pc, dd);
        ls  += __shfl_xor(ls, dd);
        cnt += __shfl_xor(cnt, dd);
    }
    if (lane == 0) { swp[w] = pc; swl[w] = ls; swc[w] = cnt; }
    __syncthreads();
    if (tid == 0) {
        float P = swp[0] + swp[1] + swp[2] + swp[3];
        float L = swl[0] + swl[1] + swl[2] + swl[3];
        int   C = swc[0] + swc[1] + swc[2] + swc[3];
        if (C) {
            atomicAdd(&n_pos[b], C);
            atomicAdd(loc_sum, L);
            atomicAdd(pos_conf, P);
        }
    }
}

// ---------- kernel 4: exact top-k sum (plain-LDS-atomic, proven fast) ------------
__device__ void wave_select(const int* hist, int nbins, int k, int* out_bin, int* out_k) {
    int lane = threadIdx.x & 63;
    int cum = 0;
    for (int c = nbins / 64 - 1; c >= 0; --c) {
        int val = hist[c * 64 + lane];
        int s = val;                           // descending suffix-sum within chunk
        for (int d = 1; d < 64; d <<= 1) {
            int t = __shfl_down(s, d);
            if (lane + d < 64) s += t;
        }
        int total = __shfl(s, 0);
        if (cum + total >= k) {
            unsigned long long mask = __ballot(cum + s >= k);
            int bl = 63 - __builtin_clzll(mask);
            int sB = __shfl(s, bl);
            int vB = __shfl(val, bl);
            if (lane == 0) {
                *out_bin = c * 64 + bl;
                *out_k = k - (cum + sB - vB);
            }
            return;
        }
        cum += total;
    }
    if (lane == 0) { *out_bin = 0; *out_k = 1; }
}

__global__ __launch_bounds__(1024) void k_select(const float* __restrict__ vneg,
                                                 const int* __restrict__ n_pos,
                                                 float* __restrict__ hard_sum,
                                                 int B, int N) {
    int b = blockIdx.x;
    const float* v = vneg + (size_t)b * N;
    __shared__ int hist[2048];
    __shared__ int bcast_bin, bcast_k;
    __shared__ float swv[16];
    __shared__ int swc[16];
    int np = n_pos[b];
    long long kk = (long long)NEG_POSK * np;
    if (kk > N) kk = N;
    int k = (int)kk;
    if (k <= 0) return;   // uniform across block
    int tid = threadIdx.x;

    for (int i = tid; i < 2048; i += 1024) hist[i] = 0;
    __syncthreads();
    for (int n = tid; n < N; n += 1024) {
        unsigned u = __float_as_uint(v[n]);
        atomicAdd(&hist[u >> 20], 1);
    }
    __syncthreads();
    if (tid < 64) wave_select(hist, 2048, k, &bcast_bin, &bcast_k);
    __syncthreads();
    int B1 = bcast_bin, k2 = bcast_k;

    for (int i = tid; i < 2048; i += 1024) hist[i] = 0;
    __syncthreads();
    for (int n = tid; n < N; n += 1024) {
        unsigned u = __float_as_uint(v[n]);
        if ((int)(u >> 20) == B1) atomicAdd(&hist[(u >> 9) & 0x7FF], 1);
    }
    __syncthreads();
    if (tid < 64) wave_select(hist, 2048, k2, &bcast_bin, &bcast_k);
    __syncthreads();
    int B2 = bcast_bin, k3 = bcast_k;
    unsigned pre = ((unsigned)B1 << 11) | (unsigned)B2;

    for (int i = tid; i < 512; i += 1024) hist[i] = 0;
    __syncthreads();
    for (int n = tid; n < N; n += 1024) {
        unsigned u = __float_as_uint(v[n]);
        if ((u >> 9) == pre) atomicAdd(&hist[u & 0x1FF], 1);
    }
    __syncthreads();
    if (tid < 64) wave_select(hist, 512, k3, &bcast_bin, &bcast_k);
    __syncthreads();
    unsigned tau_bits = (pre << 9) | (unsigned)bcast_bin;
    float tau = __uint_as_float(tau_bits);

    float ssum = 0.f; int scnt = 0;
    for (int n = tid; n < N; n += 1024) {
        float x = v[n];
        if (x > tau) { ssum += x; scnt++; }
    }
    for (int d = 1; d < 64; d <<= 1) {
        ssum += __shfl_xor(ssum, d);
        scnt += __shfl_xor(scnt, d);
    }
    int w = tid >> 6;
    if ((tid & 63) == 0) { swv[w] = ssum; swc[w] = scnt; }
    __syncthreads();
    if (tid == 0) {
        float S = 0.f; int Ct = 0;
        for (int i = 0; i < 16; ++i) { S += swv[i]; Ct += swc[i]; }
        float hb = S + (float)(k - Ct) * tau;
        atomicAdd(hard_sum, hb);
    }
}

// ---------- kernel 5: finalize ---------------------------------------------------
__global__ void k_final(const int* __restrict__ n_pos,
                        const float* __restrict__ loc_sum,
                        const float* __restrict__ pos_conf,
                        const float* __restrict__ hard_sum,
                        float* __restrict__ out, int B) {
    if (threadIdx.x == 0 && blockIdx.x == 0) {
        int tot = 0;
        for (int b = 0; b < B; ++b) tot += n_pos[b];
        float np = (float)tot;
        float loc = *loc_sum / (np * 4.0f);
        float conf = (*hard_sum + *pos_conf) / np;
        out[0] = 0.5f * loc + conf;
    }
}

extern "C" void kernel_launch(void* const* d_in, const int* in_sizes, int n_in,
                              void* d_out, int out_size, void* d_ws, size_t ws_size,
                              hipStream_t stream) {
    const float* locs_pred = (const float*)d_in[0];
    const float* cls_pred  = (const float*)d_in[1];
    const float* boxes     = (const float*)d_in[2];
    const int*   labels    = (const int*)d_in[3];
    const float* dboxes    = (const float*)d_in[4];

    int N = in_sizes[4] / 4;
    int B = in_sizes[0] / (4 * N);
    int O = in_sizes[3] / B;
    int BO = B * O;

    size_t BN = (size_t)B * N;
    char* ws = (char*)d_ws;
    int*   n_pos    = (int*)ws;                        // B ints
    float* loc_sum  = (float*)(ws + 128);
    float* pos_conf = (float*)(ws + 132);
    float* hard_sum = (float*)(ws + 136);
    float* vneg     = (float*)(ws + 256);              // BN f32
    int*   defbox_object = (int*)(ws + 256 + BN * 4);  // BO i32
    float* part_iou = (float*)(ws + 256 + BN * 4 + (size_t)BO * 4);
    int*   part_idx = (int*)(part_iou + (size_t)BO * CHUNKS);

    hipMemsetAsync(ws, 0, 256, stream);

    dim3 gop(BO, CHUNKS);
    k_obj_part<<<gop, 256, 0, stream>>>(boxes, dboxes, part_iou, part_idx, N, O);
    k_obj_reduce<<<(BO + 255) / 256, 256, 0, stream>>>(part_iou, part_idx,
                                                       defbox_object, BO);
    int tilesPerBatch = (N + TILEA - 1) / TILEA;            // 384
    int bpb = (tilesPerBatch + TPB - 1) / TPB;              // 24
    dim3 gc(B * bpb);                                       // 768 blocks, 3/CU
    if (O == 16)
        k_conf<16><<<gc, 256, 0, stream>>>(locs_pred, cls_pred, boxes, labels, dboxes,
                                           defbox_object, vneg, n_pos, loc_sum,
                                           pos_conf, N, O, bpb, tilesPerBatch);
    else
        k_conf<0><<<gc, 256, 0, stream>>>(locs_pred, cls_pred, boxes, labels, dboxes,
                                          defbox_object, vneg, n_pos, loc_sum,
                                          pos_conf, N, O, bpb, tilesPerBatch);
    k_select<<<B, 1024, 0, stream>>>(vneg, n_pos, hard_sum, B, N);
    k_final<<<1, 1, 0, stream>>>(n_pos, loc_sum, pos_conf, hard_sum, (float*)d_out, B);
}

// Round 13
// 124.074 us; speedup vs baseline: 1.7232x; 1.0307x over previous
//
#include <hip/hip_runtime.h>
#include <math.h>

#define THRESH    0.5f
#define NEG_POSK  3
#define EPSf      1e-6f
#define CCLS      81
#define TILEA     64
#define CHUNKS    16
#define TPB       16      // tiles per block; 384/16 = 24 blocks/batch, all full

__device__ __forceinline__ float iou_xy(float ax0, float ay0, float ax1, float ay1,
                                        float bx0, float by0, float bx1, float by1) {
    float lx = fmaxf(ax0, bx0), ly = fmaxf(ay0, by0);
    float rx = fminf(ax1, bx1), ry = fminf(ay1, by1);
    float w = fmaxf(rx - lx, 0.f), h = fmaxf(ry - ly, 0.f);
    float inter = w * h;
    float aa = (ax1 - ax0) * (ay1 - ay0);
    float ab = (bx1 - bx0) * (by1 - by0);
    return inter / (aa + ab - inter);
}

__device__ __forceinline__ void gload16(const void* g, void* l) {
    __builtin_amdgcn_global_load_lds(
        (const __attribute__((address_space(1))) void*)g,
        (__attribute__((address_space(3))) void*)l, 16, 0, 0);
}

// ---------- kernel 1: per-object best-anchor PARTIAL argmax (16 chunks) ----------
__global__ __launch_bounds__(256) void k_obj_part(const float* __restrict__ boxes,
                                                  const float* __restrict__ dboxes,
                                                  float* __restrict__ part_iou,
                                                  int* __restrict__ part_idx,
                                                  int N, int O) {
    int bo = blockIdx.x;
    int c  = blockIdx.y;
    const float* bb = boxes + (size_t)bo * 4;
    float ax0 = bb[0], ay0 = bb[1], ax1 = bb[2], ay1 = bb[3];
    int chunk = (N + CHUNKS - 1) / CHUNKS;
    int n0 = c * chunk;
    int n1 = min(n0 + chunk, N);
    float best = -1.f; int bi = 0x7FFFFFFF;
    for (int n = n0 + threadIdx.x; n < n1; n += 256) {
        float4 d = ((const float4*)dboxes)[n];
        float dx0 = d.x - d.z * 0.5f, dy0 = d.y - d.w * 0.5f;
        float dx1 = d.x + d.z * 0.5f, dy1 = d.y + d.w * 0.5f;
        float iou = iou_xy(ax0, ay0, ax1, ay1, dx0, dy0, dx1, dy1);
        if (iou > best) { best = iou; bi = n; }   // ascending n + strict > = first max
    }
    #pragma unroll
    for (int dd = 1; dd < 64; dd <<= 1) {
        float v2 = __shfl_xor(best, dd); int i2 = __shfl_xor(bi, dd);
        if (v2 > best || (v2 == best && i2 < bi)) { best = v2; bi = i2; }
    }
    __shared__ float sv[4]; __shared__ int si[4];
    int w = threadIdx.x >> 6;
    if ((threadIdx.x & 63) == 0) { sv[w] = best; si[w] = bi; }
    __syncthreads();
    if (threadIdx.x == 0) {
        #pragma unroll
        for (int i = 1; i < 4; ++i)
            if (sv[i] > best || (sv[i] == best && si[i] < bi)) { best = sv[i]; bi = si[i]; }
        part_iou[(size_t)bo * CHUNKS + c] = best;
        part_idx[(size_t)bo * CHUNKS + c] = bi;
    }
}

// ---------- kernel 2: reduce the 16 partials per (b,o) ---------------------------
__global__ void k_obj_reduce(const float* __restrict__ part_iou,
                             const int* __restrict__ part_idx,
                             int* __restrict__ defbox_object, int BO) {
    int bo = blockIdx.x * blockDim.x + threadIdx.x;
    if (bo >= BO) return;
    float best = -1.f; int bi = 0x7FFFFFFF;
    #pragma unroll
    for (int c = 0; c < CHUNKS; ++c) {
        float v = part_iou[(size_t)bo * CHUNKS + c];
        int  i = part_idx[(size_t)bo * CHUNKS + c];
        if (v > best || (v == best && i < bi)) { best = v; bi = i; }
    }
    defbox_object[bo] = bi;
}

// ---------- kernel 3: BARRIER-FREE per-wave pipelines ----------------------------
// Each wave owns a 16-anchor slab per tile: stages its own 5.2 KB region
// (gload_lds dest is wave-uniform -> per-wave legal) and consumes only that
// region. No __syncthreads in the loop; per-wave counted vmcnt:
//   stage = 6 VMEM, phase2 = 3 VMEM (d uncond; p/store masks non-empty on
//   every tile) -> waits: first=vmcnt(6), steady=vmcnt(9), last=vmcnt(3).
template<int OT>
__global__ __launch_bounds__(256)
void k_conf(const float* __restrict__ locs_pred,
            const float* __restrict__ cls,
            const float* __restrict__ boxes,
            const int* __restrict__ labels,
            const float* __restrict__ dboxes,
            const int* __restrict__ dbo_g,
            float* __restrict__ vneg,
            int* __restrict__ n_pos,
            float* __restrict__ loc_sum,
            float* __restrict__ pos_conf,
            int N, int O_rt, int bpb, int tilesPerBatch, long long maxF4) {
    const int O = OT ? OT : O_rt;
    __shared__ __align__(16) float sm[4][2][16 * CCLS];   // per-wave dbuf, 41.5 KB
    __shared__ float sbb[64];
    __shared__ int slab[16], sdbo[16];
    __shared__ float swl[4], swp[4];
    __shared__ int swc[4];
    const int tid = threadIdx.x;
    const int b  = blockIdx.x / bpb;
    const int t0 = (blockIdx.x % bpb) * TPB;
    const int tEnd = min(t0 + TPB, tilesPerBatch);

    if (tid < O * 4) sbb[tid] = boxes[(size_t)b * O * 4 + tid];
    else if (tid < O * 5) slab[tid - O * 4] = labels[(size_t)b * O + tid - O * 4];
    else if (tid < O * 6) sdbo[tid - O * 5] = dbo_g[(size_t)b * O + tid - O * 5];

    const int lane = tid & 63, w = tid >> 6;
    const int j = lane & 15, q = lane >> 4;

    auto stage = [&](int buf, int t) {
        // this wave's 16-anchor slab: global floats (b*N + t*64 + w*16)*81 ..
        long long base4 = (((long long)b * N + (long long)t * TILEA + w * 16)
                           * CCLS) >> 2;               // exact (divisible by 4)
        const float4* g4 = (const float4*)cls;
        float4* s4 = (float4*)&sm[w][buf][0];
        #pragma unroll
        for (int k2 = 0; k2 < 5; ++k2) {
            long long gi = base4 + k2 * 64 + lane;
            if (gi > maxF4) gi = maxF4;                // clamp (tail-of-buffer OOB)
            gload16(g4 + gi, s4 + k2 * 64);            // wave-uniform LDS base
        }
        if (lane < 4) {
            long long gi = base4 + 320 + lane;
            if (gi > maxF4) gi = maxF4;
            gload16(g4 + gi, s4 + 320);                // tail 4 float4
        }
    };

    // prologue: stage first tile, one barrier to publish sbb/slab/sdbo + drain
    stage(0, t0);
    __syncthreads();

    // hoist this lane's 4 objects (q*4 .. q*4+3) into registers
    float obx0[4], oby0[4], obx1[4], oby1[4], oarea[4];
    int odbo[4];
    #pragma unroll
    for (int oo = 0; oo < 4; ++oo) {
        int o = q * 4 + oo;
        obx0[oo] = sbb[o*4];   oby0[oo] = sbb[o*4+1];
        obx1[oo] = sbb[o*4+2]; oby1[oo] = sbb[o*4+3];
        oarea[oo] = (obx1[oo] - obx0[oo]) * (oby1[oo] - oby0[oo]);
        odbo[oo] = sdbo[o];
    }

    float pc = 0.f, ls = 0.f; int cnt = 0;

    auto phase2 = [&](int buf, int t) {
        int a0 = t * TILEA;
        int valid = min(TILEA, N - a0);
        int a = w * 16 + j;                            // anchor; 4 lanes (q) each
        bool act = a < valid;
        int n = a0 + a;
        int nc = min(n, N - 1);
        float4 d = ((const float4*)dboxes)[nc];        // VMEM #1 (uncond)
        float dx0 = d.x - d.z * 0.5f, dy0 = d.y - d.w * 0.5f;
        float dx1 = d.x + d.z * 0.5f, dy1 = d.y + d.w * 0.5f;
        float areaD = d.z * d.w;
        // division-free first-max argmax over this lane's 4 objects
        float bi = -1.f, bu = 1.f; int bsel = q * 4;
        int fs = -1;
        #pragma unroll
        for (int oo = 0; oo < 4; ++oo) {
            float lx = fmaxf(obx0[oo], dx0), ly = fmaxf(oby0[oo], dy0);
            float rx = fminf(obx1[oo], dx1), ry = fminf(oby1[oo], dy1);
            float ww = fmaxf(rx - lx, 0.f), hh = fmaxf(ry - ly, 0.f);
            float inter = ww * hh;
            float uni = oarea[oo] + areaD - inter;
            float c1 = inter * bu, c2 = bi * uni;
            if (c1 > c2) { bi = inter; bu = uni; bsel = q * 4 + oo; }  // strict >
            if (odbo[oo] == n) fs = q * 4 + oo;        // last-wins within group
        }
        // combine across the 4 q-groups (same anchor j; first-max tie->lower sel)
        #pragma unroll
        for (int dd = 16; dd < 64; dd <<= 1) {
            float oi = __shfl_xor(bi, dd), ou = __shfl_xor(bu, dd);
            int os = __shfl_xor(bsel, dd);
            int of = __shfl_xor(fs, dd);
            float c1 = oi * bu, c2 = bi * ou;
            if (c1 > c2 || (c1 == c2 && os < bsel)) { bi = oi; bu = ou; bsel = os; }
            fs = max(fs, of);                          // last-wins overall
        }
        // exp quarter-sum from this wave's private LDS region
        const float* row = &sm[w][buf][j * CCLS];
        float s = 0.f;
        if (act) {
            int c0 = q * 20;
            #pragma unroll
            for (int i = 0; i < 20; ++i) s += __expf(row[c0 + i]);
            if (q == 3) s += __expf(row[80]);
        }
        s += __shfl_xor(s, 16);
        s += __shfl_xor(s, 32);
        if (act && q == 0) {                           // mask non-empty every tile
            bool forced = fs >= 0;
            int sel = forced ? fs : bsel;
            bool meets = forced || (bi >= 0.5f * bu);  // iou >= 0.5
            int lbl = meets ? slab[sel] : 0;
            float conf = __logf(s) - row[lbl];
            bool pos = (lbl != 0);
            size_t idx = (size_t)b * N + n;
            float4 p = ((const float4*)locs_pred)[idx];   // VMEM #2
            vneg[idx] = pos ? 0.f : conf;                 // VMEM #3
            if (pos) {
                pc += conf; cnt++;
                float bx0 = sbb[sel*4], by0 = sbb[sel*4+1];
                float bx1 = sbb[sel*4+2], by1 = sbb[sel*4+3];
                float bcx = (bx0 + bx1) * 0.5f, bcy = (by0 + by1) * 0.5f;
                float bw = bx1 - bx0, bh = by1 - by0;
                float t0f = (bcx - d.x) / (d.z / 10.0f + EPSf);
                float t1f = (bcy - d.y) / (d.w / 10.0f + EPSf);
                float t2f = __logf(bw / d.z + EPSf) * 5.0f;
                float t3f = __logf(bh / d.w + EPSf) * 5.0f;
                float dd;
                dd = fabsf(p.x - t0f); ls += (dd < 1.f) ? 0.5f*dd*dd : dd - 0.5f;
                dd = fabsf(p.y - t1f); ls += (dd < 1.f) ? 0.5f*dd*dd : dd - 0.5f;
                dd = fabsf(p.z - t2f); ls += (dd < 1.f) ? 0.5f*dd*dd : dd - 0.5f;
                dd = fabsf(p.w - t3f); ls += (dd < 1.f) ? 0.5f*dd*dd : dd - 0.5f;
            }
        }
    };

    int cur = 0;
    for (int t = t0; t < tEnd; ++t) {
        bool has_next = (t + 1 < tEnd);
        if (has_next) stage(cur ^ 1, t + 1);           // issue next (6 VMEM)
        if (t == t0)
            asm volatile("s_waitcnt vmcnt(6)" ::: "memory");   // t0 drained by barrier
        else if (has_next)
            asm volatile("s_waitcnt vmcnt(9)" ::: "memory");   // allow next-stage+prev-p2
        else
            asm volatile("s_waitcnt vmcnt(3)" ::: "memory");   // allow prev-p2 only
        phase2(cur, t);
        cur ^= 1;
    }

    #pragma unroll
    for (int dd = 1; dd < 64; dd <<= 1) {
        pc  += __shfl_xor(pc, dd);
        ls  += __shfl_xor(ls, dd);
        cnt += __shfl_xor(cnt, dd);
    }
    if (lane == 0) { swp[w] = pc; swl[w] = ls; swc[w] = cnt; }
    __syncthreads();                                   // full drain + publish
    if (tid == 0) {
        float P = swp[0] + swp[1] + swp[2] + swp[3];
        float L = swl[0] + swl[1] + swl[2] + swl[3];
        int   C = swc[0] + swc[1] + swc[2] + swc[3];
        if (C) {
            atomicAdd(&n_pos[b], C);
            atomicAdd(loc_sum, L);
            atomicAdd(pos_conf, P);
        }
    }
}

// ---------- kernel 4: exact top-k sum (plain-LDS-atomic, proven fast) ------------
__device__ void wave_select(const int* hist, int nbins, int k, int* out_bin, int* out_k) {
    int lane = threadIdx.x & 63;
    int cum = 0;
    for (int c = nbins / 64 - 1; c >= 0; --c) {
        int val = hist[c * 64 + lane];
        int s = val;                           // descending suffix-sum within chunk
        for (int d = 1; d < 64; d <<= 1) {
            int t = __shfl_down(s, d);
            if (lane + d < 64) s += t;
        }
        int total = __shfl(s, 0);
        if (cum + total >= k) {
            unsigned long long mask = __ballot(cum + s >= k);
            int bl = 63 - __builtin_clzll(mask);
            int sB = __shfl(s, bl);
            int vB = __shfl(val, bl);
            if (lane == 0) {
                *out_bin = c * 64 + bl;
                *out_k = k - (cum + sB - vB);
            }
            return;
        }
        cum += total;
    }
    if (lane == 0) { *out_bin = 0; *out_k = 1; }
}

__global__ __launch_bounds__(1024) void k_select(const float* __restrict__ vneg,
                                                 const int* __restrict__ n_pos,
                                                 float* __restrict__ hard_sum,
                                                 int B, int N) {
    int b = blockIdx.x;
    const float* v = vneg + (size_t)b * N;
    __shared__ int hist[2048];
    __shared__ int bcast_bin, bcast_k;
    __shared__ float swv[16];
    __shared__ int swc[16];
    int np = n_pos[b];
    long long kk = (long long)NEG_POSK * np;
    if (kk > N) kk = N;
    int k = (int)kk;
    if (k <= 0) return;   // uniform across block
    int tid = threadIdx.x;

    for (int i = tid; i < 2048; i += 1024) hist[i] = 0;
    __syncthreads();
    for (int n = tid; n < N; n += 1024) {
        unsigned u = __float_as_uint(v[n]);
        atomicAdd(&hist[u >> 20], 1);
    }
    __syncthreads();
    if (tid < 64) wave_select(hist, 2048, k, &bcast_bin, &bcast_k);
    __syncthreads();
    int B1 = bcast_bin, k2 = bcast_k;

    for (int i = tid; i < 2048; i += 1024) hist[i] = 0;
    __syncthreads();
    for (int n = tid; n < N; n += 1024) {
        unsigned u = __float_as_uint(v[n]);
        if ((int)(u >> 20) == B1) atomicAdd(&hist[(u >> 9) & 0x7FF], 1);
    }
    __syncthreads();
    if (tid < 64) wave_select(hist, 2048, k2, &bcast_bin, &bcast_k);
    __syncthreads();
    int B2 = bcast_bin, k3 = bcast_k;
    unsigned pre = ((unsigned)B1 << 11) | (unsigned)B2;

    for (int i = tid; i < 512; i += 1024) hist[i] = 0;
    __syncthreads();
    for (int n = tid; n < N; n += 1024) {
        unsigned u = __float_as_uint(v[n]);
        if ((u >> 9) == pre) atomicAdd(&hist[u & 0x1FF], 1);
    }
    __syncthreads();
    if (tid < 64) wave_select(hist, 512, k3, &bcast_bin, &bcast_k);
    __syncthreads();
    unsigned tau_bits = (pre << 9) | (unsigned)bcast_bin;
    float tau = __uint_as_float(tau_bits);

    float ssum = 0.f; int scnt = 0;
    for (int n = tid; n < N; n += 1024) {
        float x = v[n];
        if (x > tau) { ssum += x; scnt++; }
    }
    for (int d = 1; d < 64; d <<= 1) {
        ssum += __shfl_xor(ssum, d);
        scnt += __shfl_xor(scnt, d);
    }
    int w = tid >> 6;
    if ((tid & 63) == 0) { swv[w] = ssum; swc[w] = scnt; }
    __syncthreads();
    if (tid == 0) {
        float S = 0.f; int Ct = 0;
        for (int i = 0; i < 16; ++i) { S += swv[i]; Ct += swc[i]; }
        float hb = S + (float)(k - Ct) * tau;
        atomicAdd(hard_sum, hb);
    }
}

// ---------- kernel 5: finalize ---------------------------------------------------
__global__ void k_final(const int* __restrict__ n_pos,
                        const float* __restrict__ loc_sum,
                        const float* __restrict__ pos_conf,
                        const float* __restrict__ hard_sum,
                        float* __restrict__ out, int B) {
    if (threadIdx.x == 0 && blockIdx.x == 0) {
        int tot = 0;
        for (int b = 0; b < B; ++b) tot += n_pos[b];
        float np = (float)tot;
        float loc = *loc_sum / (np * 4.0f);
        float conf = (*hard_sum + *pos_conf) / np;
        out[0] = 0.5f * loc + conf;
    }
}

extern "C" void kernel_launch(void* const* d_in, const int* in_sizes, int n_in,
                              void* d_out, int out_size, void* d_ws, size_t ws_size,
                              hipStream_t stream) {
    const float* locs_pred = (const float*)d_in[0];
    const float* cls_pred  = (const float*)d_in[1];
    const float* boxes     = (const float*)d_in[2];
    const int*   labels    = (const int*)d_in[3];
    const float* dboxes    = (const float*)d_in[4];

    int N = in_sizes[4] / 4;
    int B = in_sizes[0] / (4 * N);
    int O = in_sizes[3] / B;
    int BO = B * O;

    size_t BN = (size_t)B * N;
    char* ws = (char*)d_ws;
    int*   n_pos    = (int*)ws;                        // B ints
    float* loc_sum  = (float*)(ws + 128);
    float* pos_conf = (float*)(ws + 132);
    float* hard_sum = (float*)(ws + 136);
    float* vneg     = (float*)(ws + 256);              // BN f32
    int*   defbox_object = (int*)(ws + 256 + BN * 4);  // BO i32
    float* part_iou = (float*)(ws + 256 + BN * 4 + (size_t)BO * 4);
    int*   part_idx = (int*)(part_iou + (size_t)BO * CHUNKS);

    hipMemsetAsync(ws, 0, 256, stream);

    dim3 gop(BO, CHUNKS);
    k_obj_part<<<gop, 256, 0, stream>>>(boxes, dboxes, part_iou, part_idx, N, O);
    k_obj_reduce<<<(BO + 255) / 256, 256, 0, stream>>>(part_iou, part_idx,
                                                       defbox_object, BO);
    int tilesPerBatch = (N + TILEA - 1) / TILEA;            // 384
    int bpb = (tilesPerBatch + TPB - 1) / TPB;              // 24
    long long maxF4 = (((long long)B * N * CCLS) >> 2) - 1;
    dim3 gc(B * bpb);                                       // 768 blocks, 3/CU
    if (O == 16)
        k_conf<16><<<gc, 256, 0, stream>>>(locs_pred, cls_pred, boxes, labels, dboxes,
                                           defbox_object, vneg, n_pos, loc_sum,
                                           pos_conf, N, O, bpb, tilesPerBatch, maxF4);
    else
        k_conf<0><<<gc, 256, 0, stream>>>(locs_pred, cls_pred, boxes, labels, dboxes,
                                          defbox_object, vneg, n_pos, loc_sum,
                                          pos_conf, N, O, bpb, tilesPerBatch, maxF4);
    k_select<<<B, 1024, 0, stream>>>(vneg, n_pos, hard_sum, B, N);
    k_final<<<1, 1, 0, stream>>>(n_pos, loc_sum, pos_conf, hard_sum, (float*)d_out, B);
}